// Round 8
// baseline (535.520 us; speedup 1.0000x reference)
//
#include <hip/hip_runtime.h>
#include <cstdint>
#include <cstddef>

// ---------------------------------------------------------------------------
// TWLayer — all-MFMA pipeline (R8).
//   R8: K1/K3 rewritten BARRIER-FREE: one wave per (b,L) pair (64-thr blocks).
//       The wave owns all 256 state rows; LDS DS ops complete in issue order
//       per wave, so no __syncthreads anywhere. Compiler reordering fenced
//       with asm memory clobbers. Row stride 144->88 B (A-reads still
//       conflict-free: (22*c15+4*quad)%32 covers all even residues x4 ->
//       8-cyc min). Pad only needs FINITE bytes (B=0 annihilates), so just
//       8 B/row + 64 B tail zeroed. LDS 22.6 KB -> 7 blocks/CU.
//   K2: R7 version (BK=64, XCD swizzle) unchanged. K0 unchanged.
// ---------------------------------------------------------------------------

typedef __attribute__((ext_vector_type(8))) short short8;   // 8 x bf16
typedef __attribute__((ext_vector_type(4))) float f32x4;

#define KFENCE asm volatile("" ::: "memory")

static __device__ __forceinline__ unsigned short f2bf(float f) {
  union { float f; unsigned int u; } v; v.f = f;
  unsigned int r = v.u + 0x7FFFu + ((v.u >> 16) & 1u);   // RNE
  return (unsigned short)(r >> 16);
}
static __device__ __forceinline__ unsigned int pack2(float a, float b) {
  return (unsigned int)f2bf(a) | ((unsigned int)f2bf(b) << 16);
}

// ---- stage-permutation row maps (element-verified; g always = m&3) --------
static __device__ __forceinline__ int shuf_in(int stg, int u, int dd) {
  if (stg == 0) return ((u >> 4) << 6) | (dd << 4) | ((u & 3) << 2) | ((u >> 2) & 3);
  if (stg == 1) return ((u >> 2) << 4) | (dd << 2) | (u & 3);
  return (u << 2) | dd;                       // stg 2
}
static __device__ __forceinline__ int shuf_out(int stg, int u, int dd) {
  if (stg == 0) return (dd << 6) | ((u & 15) << 2) | (u >> 4);
  if (stg == 1) return ((u >> 4) << 6) | (dd << 4) | ((u & 3) << 2) | ((u >> 2) & 3);
  if (stg == 2) return ((u >> 2) << 4) | (dd << 2) | (u & 3);
  return (u << 2) | dd;                       // stg 3
}

// one full sweep stage, single wave: 32 ds_read_b128 + 96 MFMA into acc[16][3]
static __device__ __forceinline__ void sweep_compute(
    const unsigned short* st, const unsigned short* __restrict__ Bf,
    int lane, int c15, int quad, f32x4 acc[16][3]) {
  short8 bfr[3][2];
  #pragma unroll
  for (int nt = 0; nt < 3; ++nt) {
    bfr[nt][0] = *(const short8*)&Bf[(nt * 2 + 0) * 512 + lane * 8];
    bfr[nt][1] = *(const short8*)&Bf[(nt * 2 + 1) * 512 + lane * 8];
  }
  const int abase = c15 * 88 + quad * 16;
  #pragma unroll
  for (int mt = 0; mt < 16; ++mt) {
    const short8 a0 = *(const short8*)((const char*)st + mt * 1408 + abase);
    const short8 a1 = *(const short8*)((const char*)st + mt * 1408 + abase + 64);
    #pragma unroll
    for (int nt = 0; nt < 3; ++nt) {
      f32x4 a = {0.f, 0.f, 0.f, 0.f};
      a = __builtin_amdgcn_mfma_f32_16x16x32_bf16(a0, bfr[nt][0], a, 0, 0, 0);
      a = __builtin_amdgcn_mfma_f32_16x16x32_bf16(a1, bfr[nt][1], a, 0, 0, 0);
      acc[mt][nt] = a;
    }
  }
}

// D -> LDS for the whole wave: per (mt,nt) one b64 at the permuted row
template <int STG, bool INPUT>
static __device__ __forceinline__ void stage_writes(
    unsigned short* st, const f32x4 acc[16][3], int quad,
    const int* ddv, const int* sv) {
  #pragma unroll
  for (int mt = 0; mt < 16; ++mt) {
    const int u = mt * 4 + quad;
    #pragma unroll
    for (int nt = 0; nt < 3; ++nt) {
      if (sv[nt] < 10) {
        const int dd = ddv[nt];
        const int row = INPUT ? shuf_in(STG, u, dd) : shuf_out(STG, u, dd);
        uint2 v;
        v.x = pack2(acc[mt][nt][0], acc[mt][nt][1]);
        v.y = pack2(acc[mt][nt][2], acc[mt][nt][3]);
        *(uint2*)((char*)st + row * 88 + sv[nt] * 8) = v;
      }
    }
  }
}

// finite-pad init: 8 B/row (bytes 80..87) + 64 B tail; single wave, no barrier
static __device__ __forceinline__ void init_pad(unsigned short* st, int lane) {
  uint2 z8 = {0u, 0u};
  #pragma unroll
  for (int g = 0; g < 4; ++g)
    *(uint2*)((char*)st + (lane * 4 + g) * 88 + 80) = z8;
  if (lane < 4) {
    f32x4 z = {0.f, 0.f, 0.f, 0.f};
    *(f32x4*)((char*)st + 22528 + lane * 16) = z;
  }
}

// ---------------- K0: prep (unchanged) --------------------------------------
__global__ __launch_bounds__(256) void k0_prep(
    const float* __restrict__ ic, const float* __restrict__ oc,
    const float* __restrict__ cc, unsigned short* __restrict__ Bt,
    float* __restrict__ c2x, unsigned short* __restrict__ bf1,
    unsigned short* __restrict__ bf3, unsigned short* __restrict__ bf3l) {
  const int t = threadIdx.x;
  const int bx = blockIdx.x;
  if (bx < 1024) {
    const int dly = bx;
    const int D = (dly & 3) * 256 + ((dly >> 2) & 3) * 64 + (dly >> 4);
    const int uC = (t >> 2) * 16 + (t & 3);   // C for c''=4t+j is uC + j*4
    ushort4 pk;
    pk.x = f2bf(cc[(size_t)(uC + 0) * 1024 + D]);
    pk.y = f2bf(cc[(size_t)(uC + 4) * 1024 + D]);
    pk.z = f2bf(cc[(size_t)(uC + 8) * 1024 + D]);
    pk.w = f2bf(cc[(size_t)(uC + 12) * 1024 + D]);
    *(ushort4*)&Bt[(size_t)dly * 1024 + 4 * t] = pk;
  } else if (bx == 1024) {
    for (int idx = t; idx < 1600; idx += 256) {        // c2x[L][w][pi][s]
      int L = idx / 160, rem = idx - L * 160;
      int w = rem / 40, r2 = rem - w * 40;
      int pi = r2 / 10, s = r2 - pi * 10;
      int p1 = pi >> 1, p2 = pi & 1, c1 = w >> 1, c2v = w & 1;
      float a = 0.f;
      for (int r1 = 0; r1 < 10; ++r1)
        a += ic[L * 40 + p1 * 20 + c1 * 10 + r1] *
             ic[400 + r1 * 40 + p2 * 20 + c2v * 10 + s];
      c2x[idx] = a;
    }
  } else if (bx == 1025) {
    for (int idx = t; idx < 12288; idx += 256) {       // bf1
      int j = idx & 7, lane = (idx >> 3) & 63, kc = (idx >> 9) & 1;
      int g2 = idx >> 10, stg = g2 / 3, nt = g2 - stg * 3;
      int c15 = lane & 15, quad = lane >> 4;
      int n = nt * 16 + c15, dd = n / 12, s = n - dd * 12;
      int k = kc * 32 + quad * 8 + j, c = k >> 2, pi = k & 3;
      float v = 0.f;
      if (k < 40 && s < 10) {
        int p1 = pi >> 1, p2 = pi & 1, d1 = dd >> 1, d2 = dd & 1;
        const float* A = ic + (2 * stg + 2) * 400;
        const float* B = ic + (2 * stg + 3) * 400;
        for (int tt = 0; tt < 10; ++tt)
          v += A[c * 40 + p1 * 20 + d1 * 10 + tt] *
               B[tt * 40 + p2 * 20 + d2 * 10 + s];
      }
      bf1[idx] = f2bf(v);
    }
  } else if (bx == 1026) {
    for (int idx = t; idx < 12288; idx += 256) {       // bf3
      int j = idx & 7, lane = (idx >> 3) & 63, kc = (idx >> 9) & 1;
      int g2 = idx >> 10, stg = g2 / 3, nt = g2 - stg * 3;
      int c15 = lane & 15, quad = lane >> 4;
      int n = nt * 16 + c15, dd = n / 12, s = n - dd * 12;
      int k = kc * 32 + quad * 8 + j, c = k >> 2, pi = k & 3;
      float v = 0.f;
      if (k < 40 && s < 10) {
        int d1 = pi >> 1, d2 = pi & 1, p1 = dd >> 1, p2 = dd & 1;
        const float* A = oc + (2 * stg) * 400;
        const float* B = oc + (2 * stg + 1) * 400;
        for (int tt = 0; tt < 10; ++tt)
          v += A[c * 40 + p1 * 20 + d1 * 10 + tt] *
               B[tt * 40 + p2 * 20 + d2 * 10 + s];
      }
      bf3[idx] = f2bf(v);
    }
  } else {
    for (int idx = t; idx < 10240; idx += 256) {       // bf3l (trace folded)
      int j = idx & 7, lane = (idx >> 3) & 63, kc = (idx >> 9) & 1, L = idx >> 10;
      int c15 = lane & 15, quad = lane >> 4;
      int k = kc * 32 + quad * 8 + j, c = k >> 2, pi = k & 3;
      float v = 0.f;
      if (k < 40 && c15 < 4) {
        int dd = c15, d1 = pi >> 1, d2 = pi & 1, p1 = dd >> 1, p2 = dd & 1;
        for (int tt = 0; tt < 10; ++tt)
          v += oc[8 * 400 + c * 40 + p1 * 20 + d1 * 10 + tt] *
               oc[9 * 400 + tt * 40 + p2 * 20 + d2 * 10 + L];
      }
      bf3l[idx] = f2bf(v);
    }
  }
}

// ---------------- K1: input sweep — ONE WAVE per (b,L), no barriers --------
__global__ __launch_bounds__(64) void k1_insweep(
    const float* __restrict__ x, const float* __restrict__ c2x,
    const unsigned short* __restrict__ bf1, unsigned short* __restrict__ S) {
  __shared__ __align__(16) unsigned short st[11296];   // 256*88 + 64 B
  const int lane = threadIdx.x, bx = blockIdx.x;
  const int b = bx / 10, L = bx - b * 10;
  const int c15 = lane & 15, quad = lane >> 4;
  int ddv[3], sv[3];
  #pragma unroll
  for (int nt = 0; nt < 3; ++nt) {
    int n = nt * 16 + c15; ddv[nt] = n / 12; sv[nt] = n - ddv[nt] * 12;
  }
  init_pad(st, lane);
  // ---- stage X: absorb x bits p1..p4 via fused cores (0,1), K=4 ----
  {
    const float* xb = x + (size_t)b * 1024;
    #pragma unroll
    for (int W = 0; W < 4; ++W) {          // W = c1c2 slice
      const float* C2 = c2x + L * 160 + W * 40;
      float accx[4][10];
      #pragma unroll
      for (int g = 0; g < 4; ++g)
        #pragma unroll
        for (int s = 0; s < 10; ++s) accx[g][s] = 0.f;
      #pragma unroll
      for (int pi = 0; pi < 4; ++pi) {
        float xv[4];
        #pragma unroll
        for (int g = 0; g < 4; ++g) xv[g] = xb[pi * 256 + g * 64 + lane];
        #pragma unroll
        for (int s = 0; s < 10; ++s) {
          const float bv = C2[pi * 10 + s];
          #pragma unroll
          for (int g = 0; g < 4; ++g) accx[g][s] = fmaf(xv[g], bv, accx[g][s]);
        }
      }
      const int row = W * 64 + c15 * 4 + quad;   // (c1c2 | p7..p10 | p5p6)
      #pragma unroll
      for (int s = 0; s < 10; ++s) {
        uint2 v;
        v.x = pack2(accx[0][s], accx[1][s]);
        v.y = pack2(accx[2][s], accx[3][s]);
        *(uint2*)((char*)st + row * 88 + s * 8) = v;
      }
    }
  }
  KFENCE;
  // ---- MFMA stages 0..3 (core pairs (2,3)..(8,9)), same-wave ordering ----
  f32x4 acc[16][3];
  sweep_compute(st, bf1 + 0 * 3072, lane, c15, quad, acc);
  KFENCE; stage_writes<0, true>(st, acc, quad, ddv, sv); KFENCE;
  sweep_compute(st, bf1 + 1 * 3072, lane, c15, quad, acc);
  KFENCE; stage_writes<1, true>(st, acc, quad, ddv, sv); KFENCE;
  sweep_compute(st, bf1 + 2 * 3072, lane, c15, quad, acc);
  KFENCE; stage_writes<2, true>(st, acc, quad, ddv, sv); KFENCE;
  sweep_compute(st, bf1 + 3 * 3072, lane, c15, quad, acc);
  // final: S col c'' = u*16 + dd*4 + i  (i = c7c8)
  #pragma unroll
  for (int mt = 0; mt < 16; ++mt) {
    const int u = mt * 4 + quad;
    #pragma unroll
    for (int nt = 0; nt < 3; ++nt) {
      if (sv[nt] < 10) {
        uint2 v;
        v.x = pack2(acc[mt][nt][0], acc[mt][nt][1]);
        v.y = pack2(acc[mt][nt][2], acc[mt][nt][3]);
        *(uint2*)&S[((size_t)(bx * 10 + sv[nt])) * 1024 + u * 16 + ddv[nt] * 4] = v;
      }
    }
  }
}

// ---------------- K2: MFMA GEMM (R7: BK=64 + XCD swizzle) ------------------
__global__ __launch_bounds__(256) void k2_gemm(
    const unsigned short* __restrict__ A,   // Bt [1024][1024]  (af side)
    const unsigned short* __restrict__ B,   // S  [51200][1024] (bf side)
    unsigned short* __restrict__ U2a,       // [5120][256][32] bf16
    unsigned short* __restrict__ U2b) {     // [5120][256][8]  bf16
  __shared__ __align__(16) unsigned short Atile[2 * 128 * 32];
  __shared__ __align__(16) unsigned short Btile[2 * 128 * 32];
  const int t = threadIdx.x, bx = blockIdx.x;
  const int xcd = bx & 7;
  const int i8 = bx >> 3;                  // 0..399
  const int bm = i8 & 7;                   // 8 M-tiles
  const int bn = (i8 >> 3) * 8 + xcd;      // 400 N-tiles, partitioned by XCD
  const int wave = t >> 6, lane = t & 63;
  const int wm = wave & 1, wn = wave >> 1;

  f32x4 acc[4][4];
  #pragma unroll
  for (int i = 0; i < 4; ++i)
    #pragma unroll
    for (int j = 0; j < 4; ++j) acc[i][j] = (f32x4){0.f, 0.f, 0.f, 0.f};

  const int arow = t >> 2, achk = t & 3;
  const unsigned short* Ag = A + (size_t)(bm * 128 + arow) * 1024 + achk * 8;
  const unsigned short* Bg = B + (size_t)(bn * 128 + arow) * 1024 + achk * 8;
  char* ldsA = (char*)Atile + wave * 1024;
  char* ldsB = (char*)Btile + wave * 1024;

  for (int k0 = 0; k0 < 1024; k0 += 64) {
    #pragma unroll
    for (int kk = 0; kk < 2; ++kk) {
      const int ko = k0 + kk * 32;
      __builtin_amdgcn_global_load_lds(
          (const __attribute__((address_space(1))) void*)(Ag + ko),
          (__attribute__((address_space(3))) void*)(ldsA + kk * 8192), 16, 0, 0);
      __builtin_amdgcn_global_load_lds(
          (const __attribute__((address_space(1))) void*)(Ag + 64 * 1024 + ko),
          (__attribute__((address_space(3))) void*)(ldsA + kk * 8192 + 4096), 16, 0, 0);
      __builtin_amdgcn_global_load_lds(
          (const __attribute__((address_space(1))) void*)(Bg + ko),
          (__attribute__((address_space(3))) void*)(ldsB + kk * 8192), 16, 0, 0);
      __builtin_amdgcn_global_load_lds(
          (const __attribute__((address_space(1))) void*)(Bg + 64 * 1024 + ko),
          (__attribute__((address_space(3))) void*)(ldsB + kk * 8192 + 4096), 16, 0, 0);
    }
    __syncthreads();
    const int kq = (lane >> 4) * 8;
    #pragma unroll
    for (int kk = 0; kk < 2; ++kk) {
      short8 af[4], bf[4];
      #pragma unroll
      for (int mt = 0; mt < 4; ++mt)
        af[mt] = *(const short8*)&Atile[kk * 4096 + (wm * 64 + mt * 16 + (lane & 15)) * 32 + kq];
      #pragma unroll
      for (int nt = 0; nt < 4; ++nt)
        bf[nt] = *(const short8*)&Btile[kk * 4096 + (wn * 64 + nt * 16 + (lane & 15)) * 32 + kq];
      #pragma unroll
      for (int mt = 0; mt < 4; ++mt)
        #pragma unroll
        for (int nt = 0; nt < 4; ++nt)
          acc[mt][nt] = __builtin_amdgcn_mfma_f32_16x16x32_bf16(
              af[mt], bf[nt], acc[mt][nt], 0, 0, 0);
    }
    __syncthreads();
  }
  // epilogue: D rows = delta (i = d1d2), cols = S rows (bl, r)
  const int quad = lane >> 4;
  const int col0 = bn * 128 + wn * 64 + (lane & 15);
  const int row0 = bm * 128 + wm * 64;
  #pragma unroll
  for (int nt = 0; nt < 4; ++nt) {
    const int n = col0 + nt * 16;
    const int bl = n / 10;
    const int r = n - bl * 10;
    char* dst = (r < 8)
        ? (char*)U2a + (size_t)bl * 16384 + (size_t)r * 8
        : (char*)U2b + (size_t)bl * 4096 + (size_t)(r - 8) * 8;
    const int rb = (r < 8) ? 64 : 16;
    #pragma unroll
    for (int mt = 0; mt < 4; ++mt) {
      const int mp = (row0 + mt * 16 + quad * 4) >> 2;   // delta>>2
      uint2 v;
      v.x = pack2(acc[mt][nt][0], acc[mt][nt][1]);
      v.y = pack2(acc[mt][nt][2], acc[mt][nt][3]);
      *(uint2*)(dst + (size_t)mp * rb) = v;
    }
  }
}

// ---------------- K3: output sweep — ONE WAVE per (b,L), no barriers -------
__global__ __launch_bounds__(64) void k3_outsweep(
    const unsigned short* __restrict__ U2a, const unsigned short* __restrict__ U2b,
    const unsigned short* __restrict__ bf3, const unsigned short* __restrict__ bf3l,
    const float* __restrict__ bias, float* __restrict__ out) {
  __shared__ __align__(16) unsigned short st[11296];
  const int lane = threadIdx.x, bx = blockIdx.x;
  const int b = bx / 10, L = bx - b * 10;
  const int c15 = lane & 15, quad = lane >> 4;
  int ddv[3], sv[3];
  #pragma unroll
  for (int nt = 0; nt < 3; ++nt) {
    int n = nt * 16 + c15; ddv[nt] = n / 12; sv[nt] = n - ddv[nt] * 12;
  }
  init_pad(st, lane);
  f32x4 acc[16][3];
  // ---- stage 0: A-frags straight from global U2 (coalesced), cores (0,1) --
  {
    short8 bfr[3][2];
    #pragma unroll
    for (int nt = 0; nt < 3; ++nt) {
      bfr[nt][0] = *(const short8*)&bf3[(nt * 2 + 0) * 512 + lane * 8];
      bfr[nt][1] = *(const short8*)&bf3[(nt * 2 + 1) * 512 + lane * 8];
    }
    const char* Ua = (const char*)U2a + (size_t)bx * 16384;
    const char* Ub = (const char*)U2b + (size_t)bx * 4096;
    #pragma unroll
    for (int mt = 0; mt < 16; ++mt) {
      const int m = mt * 16 + c15;
      const short8 a0 = *(const short8*)(Ua + m * 64 + quad * 16);
      const short8 a1 = *(const short8*)(Ub + m * 16);   // quads 1-3: k>=40, B=0
      #pragma unroll
      for (int nt = 0; nt < 3; ++nt) {
        f32x4 a = {0.f, 0.f, 0.f, 0.f};
        a = __builtin_amdgcn_mfma_f32_16x16x32_bf16(a0, bfr[nt][0], a, 0, 0, 0);
        a = __builtin_amdgcn_mfma_f32_16x16x32_bf16(a1, bfr[nt][1], a, 0, 0, 0);
        acc[mt][nt] = a;
      }
    }
  }
  KFENCE; stage_writes<0, false>(st, acc, quad, ddv, sv); KFENCE;
  // ---- stages 1..3 (cores (2,3),(4,5),(6,7)) ----
  sweep_compute(st, bf3 + 1 * 3072, lane, c15, quad, acc);
  KFENCE; stage_writes<1, false>(st, acc, quad, ddv, sv); KFENCE;
  sweep_compute(st, bf3 + 2 * 3072, lane, c15, quad, acc);
  KFENCE; stage_writes<2, false>(st, acc, quad, ddv, sv); KFENCE;
  sweep_compute(st, bf3 + 3 * 3072, lane, c15, quad, acc);
  KFENCE; stage_writes<3, false>(st, acc, quad, ddv, sv); KFENCE;
  // ---- stage 4: cores (8,9) + ring trace, N=4; bias + atomicAdd ----
  {
    const unsigned short* Bf = bf3l + L * 1024;
    const short8 b0 = *(const short8*)&Bf[lane * 8];
    const short8 b1 = *(const short8*)&Bf[512 + lane * 8];
    const int abase = c15 * 88 + quad * 16;
    #pragma unroll
    for (int mt = 0; mt < 16; ++mt) {
      const short8 a0 = *(const short8*)((const char*)st + mt * 1408 + abase);
      const short8 a1 = *(const short8*)((const char*)st + mt * 1408 + abase + 64);
      f32x4 a = {0.f, 0.f, 0.f, 0.f};
      a = __builtin_amdgcn_mfma_f32_16x16x32_bf16(a0, b0, a, 0, 0, 0);
      a = __builtin_amdgcn_mfma_f32_16x16x32_bf16(a1, b1, a, 0, 0, 0);
      if (c15 < 4) {
        const int u = mt * 4 + quad;
        #pragma unroll
        for (int i = 0; i < 4; ++i) {
          const int idx = u * 16 + i * 4 + c15;   // p'1..p'10
          float v = a[i];
          if (L == 0) v += bias[idx];
          atomicAdd(&out[(size_t)b * 1024 + idx], v);
        }
      }
    }
  }
}

// ---------------- launch ----------------------------------------------------
extern "C" void kernel_launch(void* const* d_in, const int* in_sizes, int n_in,
                              void* d_out, int out_size, void* d_ws, size_t ws_size,
                              hipStream_t stream) {
  (void)in_sizes; (void)n_in; (void)ws_size;
  const float* x    = (const float*)d_in[0];
  const float* ic   = (const float*)d_in[1];
  const float* oc   = (const float*)d_in[2];
  const float* cc   = (const float*)d_in[3];
  const float* bias = (const float*)d_in[4];
  float* out = (float*)d_out;

  char* ws = (char*)d_ws;
  unsigned short* S    = (unsigned short*)(ws);              // 104857600 B
  unsigned short* U2a  = (unsigned short*)(ws + 104857600);  //  83886080 B
  unsigned short* U2b  = (unsigned short*)(ws + 188743680);  //  20971520 B
  unsigned short* Bt   = (unsigned short*)(ws + 209715200);  //   2097152 B
  float*          c2x  = (float*)(ws + 211812352);           //      6400 B
  unsigned short* bf1  = (unsigned short*)(ws + 211818752);  //     24576 B
  unsigned short* bf3  = (unsigned short*)(ws + 211843328);  //     24576 B
  unsigned short* bf3l = (unsigned short*)(ws + 211867904);  //     20480 B

  hipMemsetAsync(d_out, 0, (size_t)out_size * sizeof(float), stream);
  k0_prep<<<1028, 256, 0, stream>>>(ic, oc, cc, Bt, c2x, bf1, bf3, bf3l);
  k1_insweep<<<5120, 64, 0, stream>>>(x, c2x, bf1, S);
  k2_gemm<<<3200, 256, 0, stream>>>(Bt, S, U2a, U2b);
  k3_outsweep<<<5120, 64, 0, stream>>>(U2a, U2b, bf3, bf3l, bias, out);
}

// Round 10
// 359.094 us; speedup vs baseline: 1.4913x; 1.4913x over previous
//
#include <hip/hip_runtime.h>
#include <cstdint>
#include <cstddef>

// ---------------------------------------------------------------------------
// TWLayer — all-MFMA pipeline (R10 = R6 cooperative sweeps + dbuf state).
//   Sweeps: 4 waves cooperate on one (b,L); state ping-pongs between two
//   10240-short LDS buffers (read A -> write B) so only ONE barrier per
//   stage transition (4/kernel vs R6's 8). Row stride 80 B (no pad): the
//   kc=1 A-fragment is real data only for quad 0; quads 1-3 read a fixed
//   in-buffer address (finite, B=0 annihilates) -> no pad bytes, no init,
//   no out-of-buffer reads. LDS 40960 B -> 4 blocks/CU = 16 waves/CU.
//   K2: R7 (BK=64 + XCD swizzle, 134 us measured). K0 unchanged.
// ---------------------------------------------------------------------------

typedef __attribute__((ext_vector_type(8))) short short8;   // 8 x bf16
typedef __attribute__((ext_vector_type(4))) float f32x4;

static __device__ __forceinline__ unsigned short f2bf(float f) {
  union { float f; unsigned int u; } v; v.f = f;
  unsigned int r = v.u + 0x7FFFu + ((v.u >> 16) & 1u);   // RNE
  return (unsigned short)(r >> 16);
}
static __device__ __forceinline__ unsigned int pack2(float a, float b) {
  return (unsigned int)f2bf(a) | ((unsigned int)f2bf(b) << 16);
}

// ---- stage-permutation row maps (element-verified; g always = m&3) --------
static __device__ __forceinline__ int shuf_in(int stg, int u, int dd) {
  if (stg == 0) return ((u >> 4) << 6) | (dd << 4) | ((u & 3) << 2) | ((u >> 2) & 3);
  if (stg == 1) return ((u >> 2) << 4) | (dd << 2) | (u & 3);
  return (u << 2) | dd;                       // stg 2
}
static __device__ __forceinline__ int shuf_out(int stg, int u, int dd) {
  if (stg == 0) return (dd << 6) | ((u & 15) << 2) | (u >> 4);
  if (stg == 1) return ((u >> 4) << 6) | (dd << 4) | ((u & 3) << 2) | ((u >> 2) & 3);
  if (stg == 2) return ((u >> 2) << 4) | (dd << 2) | (u & 3);
  return (u << 2) | dd;                       // stg 3
}

// one MFMA stage from the CURRENT state buffer (stride 80 B, conflict-free:
// (20*c15+4*quad)%32 -> 8 lanes per 4-bank group). a1 is real only for
// quad==0; other quads read offset 0 (finite; B=0 kills those k-slots).
static __device__ __forceinline__ void mfma_stage80(
    const unsigned short* stc, const unsigned short* __restrict__ Bf,
    int w, int lane, int c15, int quad, f32x4 acc[4][3]) {
  short8 bfr[3][2];
  #pragma unroll
  for (int nt = 0; nt < 3; ++nt) {
    bfr[nt][0] = *(const short8*)&Bf[(nt * 2 + 0) * 512 + lane * 8];
    bfr[nt][1] = *(const short8*)&Bf[(nt * 2 + 1) * 512 + lane * 8];
  }
  #pragma unroll
  for (int rt = 0; rt < 4; ++rt) {
    const int rowA = w * 64 + rt * 16 + c15;
    const short8 a0 = *(const short8*)((const char*)stc + rowA * 80 + quad * 16);
    const int a1off = (quad == 0) ? rowA * 80 + 64 : 0;
    const short8 a1 = *(const short8*)((const char*)stc + a1off);
    #pragma unroll
    for (int nt = 0; nt < 3; ++nt) {
      f32x4 a = {0.f, 0.f, 0.f, 0.f};
      a = __builtin_amdgcn_mfma_f32_16x16x32_bf16(a0, bfr[nt][0], a, 0, 0, 0);
      a = __builtin_amdgcn_mfma_f32_16x16x32_bf16(a1, bfr[nt][1], a, 0, 0, 0);
      acc[rt][nt] = a;
    }
  }
}

// D -> DESTINATION buffer: per (rt,nt) one b64 at the permuted row
template <int STG, bool INPUT>
static __device__ __forceinline__ void stage_writes80(
    unsigned short* dst, const f32x4 acc[4][3], int w, int quad,
    const int* ddv, const int* sv) {
  #pragma unroll
  for (int rt = 0; rt < 4; ++rt) {
    const int u = w * 16 + rt * 4 + quad;
    #pragma unroll
    for (int nt = 0; nt < 3; ++nt) {
      if (sv[nt] < 10) {
        const int dd = ddv[nt];
        const int row = INPUT ? shuf_in(STG, u, dd) : shuf_out(STG, u, dd);
        uint2 v;
        v.x = pack2(acc[rt][nt][0], acc[rt][nt][1]);
        v.y = pack2(acc[rt][nt][2], acc[rt][nt][3]);
        *(uint2*)((char*)dst + row * 80 + sv[nt] * 8) = v;
      }
    }
  }
}

// ---------------- K0: prep (unchanged) --------------------------------------
__global__ __launch_bounds__(256) void k0_prep(
    const float* __restrict__ ic, const float* __restrict__ oc,
    const float* __restrict__ cc, unsigned short* __restrict__ Bt,
    float* __restrict__ c2x, unsigned short* __restrict__ bf1,
    unsigned short* __restrict__ bf3, unsigned short* __restrict__ bf3l) {
  const int t = threadIdx.x;
  const int bx = blockIdx.x;
  if (bx < 1024) {
    const int dly = bx;
    const int D = (dly & 3) * 256 + ((dly >> 2) & 3) * 64 + (dly >> 4);
    const int uC = (t >> 2) * 16 + (t & 3);   // C for c''=4t+j is uC + j*4
    ushort4 pk;
    pk.x = f2bf(cc[(size_t)(uC + 0) * 1024 + D]);
    pk.y = f2bf(cc[(size_t)(uC + 4) * 1024 + D]);
    pk.z = f2bf(cc[(size_t)(uC + 8) * 1024 + D]);
    pk.w = f2bf(cc[(size_t)(uC + 12) * 1024 + D]);
    *(ushort4*)&Bt[(size_t)dly * 1024 + 4 * t] = pk;
  } else if (bx == 1024) {
    for (int idx = t; idx < 1600; idx += 256) {        // c2x[L][w][pi][s]
      int L = idx / 160, rem = idx - L * 160;
      int w = rem / 40, r2 = rem - w * 40;
      int pi = r2 / 10, s = r2 - pi * 10;
      int p1 = pi >> 1, p2 = pi & 1, c1 = w >> 1, c2v = w & 1;
      float a = 0.f;
      for (int r1 = 0; r1 < 10; ++r1)
        a += ic[L * 40 + p1 * 20 + c1 * 10 + r1] *
             ic[400 + r1 * 40 + p2 * 20 + c2v * 10 + s];
      c2x[idx] = a;
    }
  } else if (bx == 1025) {
    for (int idx = t; idx < 12288; idx += 256) {       // bf1
      int j = idx & 7, lane = (idx >> 3) & 63, kc = (idx >> 9) & 1;
      int g2 = idx >> 10, stg = g2 / 3, nt = g2 - stg * 3;
      int c15 = lane & 15, quad = lane >> 4;
      int n = nt * 16 + c15, dd = n / 12, s = n - dd * 12;
      int k = kc * 32 + quad * 8 + j, c = k >> 2, pi = k & 3;
      float v = 0.f;
      if (k < 40 && s < 10) {
        int p1 = pi >> 1, p2 = pi & 1, d1 = dd >> 1, d2 = dd & 1;
        const float* A = ic + (2 * stg + 2) * 400;
        const float* B = ic + (2 * stg + 3) * 400;
        for (int tt = 0; tt < 10; ++tt)
          v += A[c * 40 + p1 * 20 + d1 * 10 + tt] *
               B[tt * 40 + p2 * 20 + d2 * 10 + s];
      }
      bf1[idx] = f2bf(v);
    }
  } else if (bx == 1026) {
    for (int idx = t; idx < 12288; idx += 256) {       // bf3
      int j = idx & 7, lane = (idx >> 3) & 63, kc = (idx >> 9) & 1;
      int g2 = idx >> 10, stg = g2 / 3, nt = g2 - stg * 3;
      int c15 = lane & 15, quad = lane >> 4;
      int n = nt * 16 + c15, dd = n / 12, s = n - dd * 12;
      int k = kc * 32 + quad * 8 + j, c = k >> 2, pi = k & 3;
      float v = 0.f;
      if (k < 40 && s < 10) {
        int d1 = pi >> 1, d2 = pi & 1, p1 = dd >> 1, p2 = dd & 1;
        const float* A = oc + (2 * stg) * 400;
        const float* B = oc + (2 * stg + 1) * 400;
        for (int tt = 0; tt < 10; ++tt)
          v += A[c * 40 + p1 * 20 + d1 * 10 + tt] *
               B[tt * 40 + p2 * 20 + d2 * 10 + s];
      }
      bf3[idx] = f2bf(v);
    }
  } else {
    for (int idx = t; idx < 10240; idx += 256) {       // bf3l (trace folded)
      int j = idx & 7, lane = (idx >> 3) & 63, kc = (idx >> 9) & 1, L = idx >> 10;
      int c15 = lane & 15, quad = lane >> 4;
      int k = kc * 32 + quad * 8 + j, c = k >> 2, pi = k & 3;
      float v = 0.f;
      if (k < 40 && c15 < 4) {
        int dd = c15, d1 = pi >> 1, d2 = pi & 1, p1 = dd >> 1, p2 = dd & 1;
        for (int tt = 0; tt < 10; ++tt)
          v += oc[8 * 400 + c * 40 + p1 * 20 + d1 * 10 + tt] *
               oc[9 * 400 + tt * 40 + p2 * 20 + d2 * 10 + L];
      }
      bf3l[idx] = f2bf(v);
    }
  }
}

// ---------------- K1: input sweep (coop 4 waves, dbuf, 4 barriers) ---------
__global__ __launch_bounds__(256, 4) void k1_insweep(
    const float* __restrict__ x, const float* __restrict__ c2x,
    const unsigned short* __restrict__ bf1, unsigned short* __restrict__ S) {
  __shared__ __align__(16) unsigned short st[20480];   // 2 x 10240 shorts
  const int t = threadIdx.x, bx = blockIdx.x;
  const int b = bx / 10, L = bx - b * 10;
  const int lane = t & 63, w = t >> 6;
  const int c15 = lane & 15, quad = lane >> 4;
  int ddv[3], sv[3];
  #pragma unroll
  for (int nt = 0; nt < 3; ++nt) {
    int n = nt * 16 + c15; ddv[nt] = n / 12; sv[nt] = n - ddv[nt] * 12;
  }
  unsigned short* bufA = st;
  unsigned short* bufB = st + 10240;
  // ---- stage X: absorb x bits p1..p4 via fused cores (0,1), K=4 -> bufA ---
  {
    const float* xb = x + (size_t)b * 1024;
    const float* C2 = c2x + L * 160 + w * 40;
    float accx[4][10];
    #pragma unroll
    for (int g = 0; g < 4; ++g)
      #pragma unroll
      for (int s = 0; s < 10; ++s) accx[g][s] = 0.f;
    #pragma unroll
    for (int pi = 0; pi < 4; ++pi) {
      float xv[4];
      #pragma unroll
      for (int g = 0; g < 4; ++g) xv[g] = xb[pi * 256 + g * 64 + lane];
      #pragma unroll
      for (int s = 0; s < 10; ++s) {
        const float bv = C2[pi * 10 + s];
        #pragma unroll
        for (int g = 0; g < 4; ++g) accx[g][s] = fmaf(xv[g], bv, accx[g][s]);
      }
    }
    const int row = w * 64 + c15 * 4 + quad;   // (c1c2 | p7..p10 | p5p6)
    #pragma unroll
    for (int s = 0; s < 10; ++s) {
      uint2 v;
      v.x = pack2(accx[0][s], accx[1][s]);
      v.y = pack2(accx[2][s], accx[3][s]);
      *(uint2*)((char*)bufA + row * 80 + s * 8) = v;
    }
  }
  __syncthreads();
  f32x4 acc[4][3];
  // stage 0: A -> B
  mfma_stage80(bufA, bf1 + 0 * 3072, w, lane, c15, quad, acc);
  stage_writes80<0, true>(bufB, acc, w, quad, ddv, sv);
  __syncthreads();
  // stage 1: B -> A
  mfma_stage80(bufB, bf1 + 1 * 3072, w, lane, c15, quad, acc);
  stage_writes80<1, true>(bufA, acc, w, quad, ddv, sv);
  __syncthreads();
  // stage 2: A -> B
  mfma_stage80(bufA, bf1 + 2 * 3072, w, lane, c15, quad, acc);
  stage_writes80<2, true>(bufB, acc, w, quad, ddv, sv);
  __syncthreads();
  // stage 3: B -> S (global), col c'' = u*16 + dd*4 + i  (i = c7c8)
  mfma_stage80(bufB, bf1 + 3 * 3072, w, lane, c15, quad, acc);
  #pragma unroll
  for (int rt = 0; rt < 4; ++rt) {
    const int u = w * 16 + rt * 4 + quad;
    #pragma unroll
    for (int nt = 0; nt < 3; ++nt) {
      if (sv[nt] < 10) {
        uint2 v;
        v.x = pack2(acc[rt][nt][0], acc[rt][nt][1]);
        v.y = pack2(acc[rt][nt][2], acc[rt][nt][3]);
        *(uint2*)&S[((size_t)(bx * 10 + sv[nt])) * 1024 + u * 16 + ddv[nt] * 4] = v;
      }
    }
  }
}

// ---------------- K2: MFMA GEMM (R7: BK=64 + XCD swizzle) ------------------
__global__ __launch_bounds__(256) void k2_gemm(
    const unsigned short* __restrict__ A,   // Bt [1024][1024]  (af side)
    const unsigned short* __restrict__ B,   // S  [51200][1024] (bf side)
    unsigned short* __restrict__ U2a,       // [5120][256][32] bf16
    unsigned short* __restrict__ U2b) {     // [5120][256][8]  bf16
  __shared__ __align__(16) unsigned short Atile[2 * 128 * 32];
  __shared__ __align__(16) unsigned short Btile[2 * 128 * 32];
  const int t = threadIdx.x, bx = blockIdx.x;
  const int xcd = bx & 7;
  const int i8 = bx >> 3;                  // 0..399
  const int bm = i8 & 7;                   // 8 M-tiles
  const int bn = (i8 >> 3) * 8 + xcd;      // 400 N-tiles, partitioned by XCD
  const int wave = t >> 6, lane = t & 63;
  const int wm = wave & 1, wn = wave >> 1;

  f32x4 acc[4][4];
  #pragma unroll
  for (int i = 0; i < 4; ++i)
    #pragma unroll
    for (int j = 0; j < 4; ++j) acc[i][j] = (f32x4){0.f, 0.f, 0.f, 0.f};

  const int arow = t >> 2, achk = t & 3;
  const unsigned short* Ag = A + (size_t)(bm * 128 + arow) * 1024 + achk * 8;
  const unsigned short* Bg = B + (size_t)(bn * 128 + arow) * 1024 + achk * 8;
  char* ldsA = (char*)Atile + wave * 1024;
  char* ldsB = (char*)Btile + wave * 1024;

  for (int k0 = 0; k0 < 1024; k0 += 64) {
    #pragma unroll
    for (int kk = 0; kk < 2; ++kk) {
      const int ko = k0 + kk * 32;
      __builtin_amdgcn_global_load_lds(
          (const __attribute__((address_space(1))) void*)(Ag + ko),
          (__attribute__((address_space(3))) void*)(ldsA + kk * 8192), 16, 0, 0);
      __builtin_amdgcn_global_load_lds(
          (const __attribute__((address_space(1))) void*)(Ag + 64 * 1024 + ko),
          (__attribute__((address_space(3))) void*)(ldsA + kk * 8192 + 4096), 16, 0, 0);
      __builtin_amdgcn_global_load_lds(
          (const __attribute__((address_space(1))) void*)(Bg + ko),
          (__attribute__((address_space(3))) void*)(ldsB + kk * 8192), 16, 0, 0);
      __builtin_amdgcn_global_load_lds(
          (const __attribute__((address_space(1))) void*)(Bg + 64 * 1024 + ko),
          (__attribute__((address_space(3))) void*)(ldsB + kk * 8192 + 4096), 16, 0, 0);
    }
    __syncthreads();
    const int kq = (lane >> 4) * 8;
    #pragma unroll
    for (int kk = 0; kk < 2; ++kk) {
      short8 af[4], bf[4];
      #pragma unroll
      for (int mt = 0; mt < 4; ++mt)
        af[mt] = *(const short8*)&Atile[kk * 4096 + (wm * 64 + mt * 16 + (lane & 15)) * 32 + kq];
      #pragma unroll
      for (int nt = 0; nt < 4; ++nt)
        bf[nt] = *(const short8*)&Btile[kk * 4096 + (wn * 64 + nt * 16 + (lane & 15)) * 32 + kq];
      #pragma unroll
      for (int mt = 0; mt < 4; ++mt)
        #pragma unroll
        for (int nt = 0; nt < 4; ++nt)
          acc[mt][nt] = __builtin_amdgcn_mfma_f32_16x16x32_bf16(
              af[mt], bf[nt], acc[mt][nt], 0, 0, 0);
    }
    __syncthreads();
  }
  // epilogue: D rows = delta (i = d1d2), cols = S rows (bl, r)
  const int quad = lane >> 4;
  const int col0 = bn * 128 + wn * 64 + (lane & 15);
  const int row0 = bm * 128 + wm * 64;
  #pragma unroll
  for (int nt = 0; nt < 4; ++nt) {
    const int n = col0 + nt * 16;
    const int bl = n / 10;
    const int r = n - bl * 10;
    char* dst = (r < 8)
        ? (char*)U2a + (size_t)bl * 16384 + (size_t)r * 8
        : (char*)U2b + (size_t)bl * 4096 + (size_t)(r - 8) * 8;
    const int rb = (r < 8) ? 64 : 16;
    #pragma unroll
    for (int mt = 0; mt < 4; ++mt) {
      const int mp = (row0 + mt * 16 + quad * 4) >> 2;   // delta>>2
      uint2 v;
      v.x = pack2(acc[mt][nt][0], acc[mt][nt][1]);
      v.y = pack2(acc[mt][nt][2], acc[mt][nt][3]);
      *(uint2*)(dst + (size_t)mp * rb) = v;
    }
  }
}

// ---------------- K3: output sweep (coop 4 waves, dbuf, 4 barriers) --------
__global__ __launch_bounds__(256, 4) void k3_outsweep(
    const unsigned short* __restrict__ U2a, const unsigned short* __restrict__ U2b,
    const unsigned short* __restrict__ bf3, const unsigned short* __restrict__ bf3l,
    const float* __restrict__ bias, float* __restrict__ out) {
  __shared__ __align__(16) unsigned short st[20480];
  const int t = threadIdx.x, bx = blockIdx.x;
  const int b = bx / 10, L = bx - b * 10;
  const int lane = t & 63, w = t >> 6;
  const int c15 = lane & 15, quad = lane >> 4;
  int ddv[3], sv[3];
  #pragma unroll
  for (int nt = 0; nt < 3; ++nt) {
    int n = nt * 16 + c15; ddv[nt] = n / 12; sv[nt] = n - ddv[nt] * 12;
  }
  unsigned short* bufA = st;
  unsigned short* bufB = st + 10240;
  f32x4 acc[4][3];
  // ---- stage 0: A-frags from global U2 (coalesced), cores (0,1) -> bufA ---
  {
    short8 bfr[3][2];
    #pragma unroll
    for (int nt = 0; nt < 3; ++nt) {
      bfr[nt][0] = *(const short8*)&bf3[(nt * 2 + 0) * 512 + lane * 8];
      bfr[nt][1] = *(const short8*)&bf3[(nt * 2 + 1) * 512 + lane * 8];
    }
    const char* Ua = (const char*)U2a + (size_t)bx * 16384;
    const char* Ub = (const char*)U2b + (size_t)bx * 4096;
    #pragma unroll
    for (int rt = 0; rt < 4; ++rt) {
      const int m = w * 64 + rt * 16 + c15;
      const short8 a0 = *(const short8*)(Ua + m * 64 + quad * 16);
      const short8 a1 = *(const short8*)(Ub + m * 16);   // quads 1-3: k>=40, B=0
      #pragma unroll
      for (int nt = 0; nt < 3; ++nt) {
        f32x4 a = {0.f, 0.f, 0.f, 0.f};
        a = __builtin_amdgcn_mfma_f32_16x16x32_bf16(a0, bfr[nt][0], a, 0, 0, 0);
        a = __builtin_amdgcn_mfma_f32_16x16x32_bf16(a1, bfr[nt][1], a, 0, 0, 0);
        acc[rt][nt] = a;
      }
    }
    stage_writes80<0, false>(bufA, acc, w, quad, ddv, sv);
  }
  __syncthreads();
  // stage 1: A -> B
  mfma_stage80(bufA, bf3 + 1 * 3072, w, lane, c15, quad, acc);
  stage_writes80<1, false>(bufB, acc, w, quad, ddv, sv);
  __syncthreads();
  // stage 2: B -> A
  mfma_stage80(bufB, bf3 + 2 * 3072, w, lane, c15, quad, acc);
  stage_writes80<2, false>(bufA, acc, w, quad, ddv, sv);
  __syncthreads();
  // stage 3: A -> B
  mfma_stage80(bufA, bf3 + 3 * 3072, w, lane, c15, quad, acc);
  stage_writes80<3, false>(bufB, acc, w, quad, ddv, sv);
  __syncthreads();
  // ---- stage 4: cores (8,9) + ring trace from bufB; bias + atomicAdd ----
  {
    const unsigned short* Bf = bf3l + L * 1024;
    const short8 b0 = *(const short8*)&Bf[lane * 8];
    const short8 b1 = *(const short8*)&Bf[512 + lane * 8];
    #pragma unroll
    for (int rt = 0; rt < 4; ++rt) {
      const int rowA = w * 64 + rt * 16 + c15;
      const short8 a0 = *(const short8*)((const char*)bufB + rowA * 80 + quad * 16);
      const int a1off = (quad == 0) ? rowA * 80 + 64 : 0;
      const short8 a1 = *(const short8*)((const char*)bufB + a1off);
      f32x4 a = {0.f, 0.f, 0.f, 0.f};
      a = __builtin_amdgcn_mfma_f32_16x16x32_bf16(a0, b0, a, 0, 0, 0);
      a = __builtin_amdgcn_mfma_f32_16x16x32_bf16(a1, b1, a, 0, 0, 0);
      if (c15 < 4) {
        const int u = w * 16 + rt * 4 + quad;
        #pragma unroll
        for (int i = 0; i < 4; ++i) {
          const int oidx = u * 16 + i * 4 + c15;   // p'1..p'10
          float v = a[i];
          if (L == 0) v += bias[oidx];
          atomicAdd(&out[(size_t)b * 1024 + oidx], v);
        }
      }
    }
  }
}

// ---------------- launch ----------------------------------------------------
extern "C" void kernel_launch(void* const* d_in, const int* in_sizes, int n_in,
                              void* d_out, int out_size, void* d_ws, size_t ws_size,
                              hipStream_t stream) {
  (void)in_sizes; (void)n_in; (void)ws_size;
  const float* x    = (const float*)d_in[0];
  const float* ic   = (const float*)d_in[1];
  const float* oc   = (const float*)d_in[2];
  const float* cc   = (const float*)d_in[3];
  const float* bias = (const float*)d_in[4];
  float* out = (float*)d_out;

  char* ws = (char*)d_ws;
  unsigned short* S    = (unsigned short*)(ws);              // 104857600 B
  unsigned short* U2a  = (unsigned short*)(ws + 104857600);  //  83886080 B
  unsigned short* U2b  = (unsigned short*)(ws + 188743680);  //  20971520 B
  unsigned short* Bt   = (unsigned short*)(ws + 209715200);  //   2097152 B
  float*          c2x  = (float*)(ws + 211812352);           //      6400 B
  unsigned short* bf1  = (unsigned short*)(ws + 211818752);  //     24576 B
  unsigned short* bf3  = (unsigned short*)(ws + 211843328);  //     24576 B
  unsigned short* bf3l = (unsigned short*)(ws + 211867904);  //     20480 B

  hipMemsetAsync(d_out, 0, (size_t)out_size * sizeof(float), stream);
  k0_prep<<<1028, 256, 0, stream>>>(ic, oc, cc, Bt, c2x, bf1, bf3, bf3l);
  k1_insweep<<<5120, 256, 0, stream>>>(x, c2x, bf1, S);
  k2_gemm<<<3200, 256, 0, stream>>>(Bt, S, U2a, U2b);
  k3_outsweep<<<5120, 256, 0, stream>>>(U2a, U2b, bf3, bf3l, bias, out);
}